// Round 9
// baseline (149.163 us; speedup 1.0000x reference)
//
#include <hip/hip_runtime.h>
#include <hip/hip_bf16.h>
#include <cstdint>

typedef float f32x4 __attribute__((ext_vector_type(4)));
typedef __bf16 bf16x8 __attribute__((ext_vector_type(8)));
typedef uint32_t uint2v __attribute__((ext_vector_type(2)));

#define MFMA_K32(A, B, C) __builtin_amdgcn_mfma_f32_16x16x32_bf16((A), (B), (C), 0, 0, 0)

#if __has_builtin(__builtin_amdgcn_exp2f)
#define EXP2(x) __builtin_amdgcn_exp2f(x)
#else
#define EXP2(x) exp2f(x)
#endif

// round-to-nearest-even f32 -> bf16 bits
static __device__ __forceinline__ uint16_t f2b(float f) {
    uint32_t u = __float_as_uint(f);
    uint32_t r = (u + 0x7fffu + ((u >> 16) & 1u)) >> 16;
    return (uint16_t)r;
}

// pack two f32 -> bf16x2 dword (low = a, high = b), RNE.
// m240: no builtin on gfx950 -- MUST be inline asm, else a ~7-op SW fallback
// compiles and dominates the VALU budget (R8: flash 65->49.6 us from this).
static __device__ __forceinline__ uint32_t packbf(float a, float b) {
    uint32_t r;
    asm("v_cvt_pk_bf16_f32 %0, %1, %2" : "=v"(r) : "v"(a), "v"(b));
    return r;
}

// ---------------- kernel 0: weights f32->bf16 + PE table -----------------
__global__ __launch_bounds__(256) void wconv_pe(const float* __restrict__ wq,
                                                const float* __restrict__ wk,
                                                const float* __restrict__ wv,
                                                const float* __restrict__ wo,
                                                uint16_t* __restrict__ dst,
                                                float* __restrict__ pet) {
    int bid = blockIdx.x, t = threadIdx.x;
    if (bid < 1024) {
        int idx = bid * 256 + t;
        int which = idx >> 16, off = idx & 65535;
        const float* s = (which == 0) ? wq : (which == 1) ? wk : (which == 2) ? wv : wo;
        dst[idx] = f2b(s[off]);
    } else {
        int idx = (bid - 1024) * 256 + t;   // 0..16383
        int cc = idx >> 6, p = idx & 63;
        int i = (cc & 127) >> 1;
        float dt = __expf((float)(2 * i) * -0.07195578415606394f);  // -(ln 1e4)/128
        float sv, cv;
        __sincosf((float)p * dt, &sv, &cv);
        pet[idx] = (cc & 1) ? cv : sv;
    }
}

// ---------------- kernel 1: QKV projection straight from x ---------------
// grid (128 mtiles, 4 otiles), 256 thr = 4 waves. D[o][n].
// A-fragments built on the fly: af = bf16(x + PE), PE from the pet table.
// This removes the peadd kernel and the tok intermediate entirely.
__global__ __launch_bounds__(256) void qkv_gemm(const float* __restrict__ x,
                                                const float* __restrict__ pet,
                                                const uint16_t* __restrict__ Wall,
                                                const float* __restrict__ bq,
                                                const float* __restrict__ bk,
                                                const float* __restrict__ bv,
                                                uint16_t* __restrict__ qo,
                                                uint16_t* __restrict__ ko,
                                                uint16_t* __restrict__ vo) {
    __shared__ __align__(16) uint16_t WS[64][264];
    int tid = threadIdx.x, wv = tid >> 6, lane = tid & 63;
    int c16 = lane & 15, quad = lane >> 4;
    int M0 = blockIdx.x * 64 + wv * 16;
    int O0 = blockIdx.y * 64;
    int bb = M0 >> 12, n = (M0 + c16) & 4095;
    int nl = n & 63, posh = (n >> 6) & 63;
    const float* xb = x + ((size_t)bb << 20);  // [256][4096] image for this batch
    bf16x8 af[8];
#pragma unroll
    for (int kk = 0; kk < 8; ++kk) {
        union { uint32_t u[4]; bf16x8 v; } a;
#pragma unroll
        for (int j = 0; j < 4; ++j) {
            int cc0 = kk * 32 + quad * 8 + 2 * j;
            float pe0 = pet[cc0 * 64 + ((cc0 & 128) ? posh : nl)];
            float pe1 = pet[(cc0 + 1) * 64 + (((cc0 + 1) & 128) ? posh : nl)];
            float v0 = xb[(size_t)cc0 * 4096 + n] + pe0;
            float v1 = xb[(size_t)(cc0 + 1) * 4096 + n] + pe1;
            a.u[j] = packbf(v0, v1);
        }
        af[kk] = a.v;
    }
    f32x4 zero = {0.f, 0.f, 0.f, 0.f};
    int srow = tid >> 5, sch = (tid & 31) << 3;  // staging: 2048 elems/pass
    for (int mat = 0; mat < 3; ++mat) {
        const uint16_t* Wg = Wall + (size_t)mat * 65536 + (size_t)O0 * 256;
        __syncthreads();  // previous WS readers done
#pragma unroll
        for (int p = 0; p < 8; ++p)
            *(bf16x8*)(&WS[p * 8 + srow][sch]) = *(const bf16x8*)(Wg + (p * 8 + srow) * 256 + sch);
        __syncthreads();
        f32x4 acc[4] = {zero, zero, zero, zero};
#pragma unroll
        for (int kk = 0; kk < 8; ++kk) {
            int k0 = kk * 32 + quad * 8;
#pragma unroll
            for (int nb = 0; nb < 4; ++nb)
                acc[nb] = MFMA_K32(*(const bf16x8*)(&WS[nb * 16 + c16][k0]),
                                   af[kk], acc[nb]);  // D[o][n]
        }
        const float* bias = (mat == 0) ? bq : (mat == 1) ? bk : bv;
        if (mat < 2) {
            // q gets 1/sqrt(32)*log2(e) folded in (softmax uses exp2)
            float scale = (mat == 0) ? 0.25505654134660127f : 1.0f;
            uint16_t* dst = (mat == 0) ? qo : ko;
#pragma unroll
            for (int nb = 0; nb < 4; ++nb) {
                int o = O0 + nb * 16 + quad * 4;          // o..o+3, same head
                f32x4 bi = *(const f32x4*)(bias + o);
                int h = o >> 5, dd = o & 31;
                uint2v pk;
                pk[0] = packbf((acc[nb][0] + bi[0]) * scale, (acc[nb][1] + bi[1]) * scale);
                pk[1] = packbf((acc[nb][2] + bi[2]) * scale, (acc[nb][3] + bi[3]) * scale);
                *(uint2v*)(dst + ((size_t)(bb * 8 + h) * 4096 + n) * 32 + dd) = pk;
            }
        } else {
            // V^T [bh,d,n]
#pragma unroll
            for (int nb = 0; nb < 4; ++nb)
#pragma unroll
                for (int r = 0; r < 4; ++r) {
                    int o = O0 + nb * 16 + quad * 4 + r;
                    vo[((size_t)(bb * 8 + (o >> 5)) * 32 + (o & 31)) * 4096 + n] =
                        f2b(acc[nb][r] + bias[o]);
                }
        }
    }
}

// ---------------- kernel 2: flash attention, LDS-staged + in-block k-split
// grid (32 qtiles of 128, 16 bh), block 512 = 8 waves; wave owns 32 q rows.
// K32 path everywhere: QK A-operand rows are PERMUTED so each lane's two
// 4-element sub-chunk score registers cover physical k = quad*8..quad*8+7 ==
// the 16x16x32 A-fragment layout. Dual q-blocks interleaved. Row-sum l via
// ones-frag MFMA.
__global__ __launch_bounds__(512, 4) void flash(const uint16_t* __restrict__ qb,
                                                const uint16_t* __restrict__ kb,
                                                const uint16_t* __restrict__ vtb,
                                                uint16_t* __restrict__ concat) {
    // per half: KT[2][64][40] (10240 B) + VT[2][32][72] (9216 B) = 19456 B
    __shared__ __align__(16) char smem[38912];
    int tid = threadIdx.x, wv = tid >> 6, lane = tid & 63;
    int c16 = lane & 15, quad = lane >> 4;
    int half = tid >> 8, t2 = tid & 255;
    int bh = blockIdx.y;
    int q0 = (blockIdx.x << 7) + (wv & 3) * 32;
    size_t base = (size_t)bh << 12;

    uint16_t* KT = (uint16_t*)(smem + half * 19456);          // [2][64][40]
    uint16_t* VT = (uint16_t*)(smem + half * 19456 + 10240);  // [2][32][72]

    const uint16_t* kgp = kb + (base + (size_t)half * 2048 + (t2 >> 2)) * 32 + (t2 & 3) * 8;
    const uint16_t* vgp = vtb + ((size_t)bh * 32 + (t2 >> 3)) * 4096 + half * 2048 + (t2 & 7) * 8;
    uint16_t* kls = KT + (t2 >> 2) * 40 + (t2 & 3) * 8;   // + buf*2560
    uint16_t* vls = VT + (t2 >> 3) * 72 + (t2 & 7) * 8;   // + buf*2304

    bf16x8 qf0 = *(const bf16x8*)(qb + (base + q0 + c16) * 32 + quad * 8);
    bf16x8 qf1 = *(const bf16x8*)(qb + (base + q0 + 16 + c16) * 32 + quad * 8);

    // permuted K-row base for the QK A-operand
    int rbase = ((c16 >> 2) << 3) + (c16 & 3);

    union { uint32_t u[4]; bf16x8 v; } onesu;
    onesu.u[0] = 0x3F803F80u; onesu.u[1] = 0x3F803F80u;
    onesu.u[2] = 0x3F803F80u; onesu.u[3] = 0x3F803F80u;
    bf16x8 ones = onesu.v;

    f32x4 zero = {0.f, 0.f, 0.f, 0.f};
    f32x4 o00 = zero, o01 = zero, o10 = zero, o11 = zero;
    f32x4 oS0 = zero, oS1 = zero;

    // prologue: stage tile 0 into buf 0
    {
        bf16x8 kr = *(const bf16x8*)kgp;
        bf16x8 vr = *(const bf16x8*)vgp;
        *(bf16x8*)kls = kr;
        *(bf16x8*)vls = vr;
    }
    __syncthreads();

    for (int kt = 0; kt < 32; ++kt) {
        int cur = kt & 1;
        int kn = (kt + 1) & 31;  // last iter re-loads tile 0 (in-bounds, unused)
        bf16x8 kr = *(const bf16x8*)(kgp + (size_t)kn * 2048);
        bf16x8 vr = *(const bf16x8*)(vgp + kn * 64);
        const uint16_t* kfp = KT + cur * 2560 + rbase * 40 + quad * 8;
        const uint16_t* vfp = VT + cur * 2304 + c16 * 72 + quad * 8;
        bf16x8 kf[4], vA[2], vB[2];
        kf[0] = *(const bf16x8*)(kfp);                 // p0 j0: rows rbase
        kf[1] = *(const bf16x8*)(kfp + 160);           // p0 j1: rows rbase+4
        kf[2] = *(const bf16x8*)(kfp + 1280);          // p1 j0: rows rbase+32
        kf[3] = *(const bf16x8*)(kfp + 1440);          // p1 j1: rows rbase+36
        vA[0] = *(const bf16x8*)(vfp);                 // d=c16,    seq quad*8
        vA[1] = *(const bf16x8*)(vfp + 32);            // d=c16,    seq 32+quad*8
        vB[0] = *(const bf16x8*)(vfp + 1152);          // d=16+c16, seq quad*8
        vB[1] = *(const bf16x8*)(vfp + 1152 + 32);     // d=16+c16, seq 32+quad*8

        // QK^T for both q-blocks: 8 independent MFMAs
        f32x4 s0[4], s1[4];
#pragma unroll
        for (int c = 0; c < 4; ++c) s0[c] = MFMA_K32(kf[c], qf0, zero);
#pragma unroll
        for (int c = 0; c < 4; ++c) s1[c] = MFMA_K32(kf[c], qf1, zero);

        // exp2 -> pack -> PV, two independent chains per p
#pragma unroll
        for (int p = 0; p < 2; ++p) {
#pragma unroll
            for (int r = 0; r < 4; ++r) {
                s0[2 * p][r] = EXP2(s0[2 * p][r]);
                s0[2 * p + 1][r] = EXP2(s0[2 * p + 1][r]);
                s1[2 * p][r] = EXP2(s1[2 * p][r]);
                s1[2 * p + 1][r] = EXP2(s1[2 * p + 1][r]);
            }
            union { bf16x8 v; uint32_t u[4]; } pa0, pa1;
            pa0.u[0] = packbf(s0[2 * p][0], s0[2 * p][1]);
            pa0.u[1] = packbf(s0[2 * p][2], s0[2 * p][3]);
            pa0.u[2] = packbf(s0[2 * p + 1][0], s0[2 * p + 1][1]);
            pa0.u[3] = packbf(s0[2 * p + 1][2], s0[2 * p + 1][3]);
            pa1.u[0] = packbf(s1[2 * p][0], s1[2 * p][1]);
            pa1.u[1] = packbf(s1[2 * p][2], s1[2 * p][3]);
            pa1.u[2] = packbf(s1[2 * p + 1][0], s1[2 * p + 1][1]);
            pa1.u[3] = packbf(s1[2 * p + 1][2], s1[2 * p + 1][3]);
            o00 = MFMA_K32(pa0.v, vA[p], o00);
            o01 = MFMA_K32(pa0.v, vB[p], o01);
            oS0 = MFMA_K32(pa0.v, ones, oS0);
            o10 = MFMA_K32(pa1.v, vA[p], o10);
            o11 = MFMA_K32(pa1.v, vB[p], o11);
            oS1 = MFMA_K32(pa1.v, ones, oS1);
        }

        *(bf16x8*)(kls + (cur ^ 1) * 2560) = kr;
        *(bf16x8*)(vls + (cur ^ 1) * 2304) = vr;
        __syncthreads();
    }

    // combine the two k-halves via LDS (staging area is dead now)
    float* ov = (float*)smem;  // [4][64][25] = 25600 B
    if (wv >= 4) {
        float* d = ov + ((wv - 4) * 64 + lane) * 25;
#pragma unroll
        for (int r = 0; r < 4; ++r) {
            d[r] = o00[r]; d[4 + r] = o01[r]; d[8 + r] = o10[r]; d[12 + r] = o11[r];
            d[16 + r] = oS0[r]; d[20 + r] = oS1[r];
        }
    }
    __syncthreads();
    if (wv < 4) {
        const float* s = ov + (wv * 64 + lane) * 25;
#pragma unroll
        for (int r = 0; r < 4; ++r) {
            o00[r] += s[r]; o01[r] += s[4 + r]; o10[r] += s[8 + r]; o11[r] += s[12 + r];
            oS0[r] += s[16 + r]; oS1[r] += s[20 + r];
        }
        int h = bh & 7, bb = bh >> 3;
#pragma unroll
        for (int r = 0; r < 4; ++r) {
            float i0 = 1.f / oS0[r];   // l row-aligned with o rows: no shuffle
            float i1 = 1.f / oS1[r];
            int n = q0 + quad * 4 + r;
            size_t row0 = ((size_t)bb * 4096 + n) * 256 + h * 32;
            size_t row1 = ((size_t)bb * 4096 + n + 16) * 256 + h * 32;
            concat[row0 + c16]      = f2b(o00[r] * i0);
            concat[row0 + 16 + c16] = f2b(o01[r] * i0);
            concat[row1 + c16]      = f2b(o10[r] * i1);
            concat[row1 + 16 + c16] = f2b(o11[r] * i1);
        }
    }
}

// ---------------- kernel 3: output projection, W LDS-staged --------------
__global__ __launch_bounds__(256) void proj_gemm(const uint16_t* __restrict__ concat,
                                                 const uint16_t* __restrict__ Wo,
                                                 const float* __restrict__ bo,
                                                 float* __restrict__ out) {
    __shared__ __align__(16) uint16_t WS[64][264];
    int tid = threadIdx.x, wv = tid >> 6, lane = tid & 63;
    int c16 = lane & 15, quad = lane >> 4;
    int M0 = blockIdx.x * 64 + wv * 16;
    int O0 = blockIdx.y * 64;
    int srow = tid >> 5, sch = (tid & 31) << 3;
    const uint16_t* Wg = Wo + (size_t)O0 * 256;
#pragma unroll
    for (int p = 0; p < 8; ++p)
        *(bf16x8*)(&WS[p * 8 + srow][sch]) = *(const bf16x8*)(Wg + (p * 8 + srow) * 256 + sch);
    const uint16_t* crow = concat + (size_t)(M0 + c16) * 256;
    bf16x8 af[8];
#pragma unroll
    for (int kk = 0; kk < 8; ++kk) af[kk] = *(const bf16x8*)(crow + kk * 32 + quad * 8);
    __syncthreads();
    f32x4 zero = {0.f, 0.f, 0.f, 0.f};
    f32x4 acc[4] = {zero, zero, zero, zero};
#pragma unroll
    for (int kk = 0; kk < 8; ++kk) {
        int k0 = kk * 32 + quad * 8;
#pragma unroll
        for (int nb = 0; nb < 4; ++nb)
            acc[nb] = MFMA_K32(*(const bf16x8*)(&WS[nb * 16 + c16][k0]),
                               af[kk], acc[nb]);  // D[o][token]
    }
    int bb = M0 >> 12, n = (M0 + c16) & 4095;
#pragma unroll
    for (int nb = 0; nb < 4; ++nb)
#pragma unroll
        for (int r = 0; r < 4; ++r) {
            int o = O0 + nb * 16 + quad * 4 + r;
            out[((size_t)(bb * 256 + o) << 12) + n] = acc[nb][r] + bo[o];
        }
}

extern "C" void kernel_launch(void* const* d_in, const int* in_sizes, int n_in,
                              void* d_out, int out_size, void* d_ws, size_t ws_size,
                              hipStream_t stream) {
    const float* x  = (const float*)d_in[0];
    const float* Wq = (const float*)d_in[1];
    const float* bq = (const float*)d_in[2];
    const float* Wk = (const float*)d_in[3];
    const float* bk = (const float*)d_in[4];
    const float* Wv = (const float*)d_in[5];
    const float* bv = (const float*)d_in[6];
    const float* Wo = (const float*)d_in[7];
    const float* bo = (const float*)d_in[8];
    float* out = (float*)d_out;

    uint16_t* ws   = (uint16_t*)d_ws;
    uint16_t* Wb   = ws;                  // 4*65536 bf16
    uint16_t* q    = Wb + 4 * 65536;      // [bh,n,d]
    uint16_t* k    = q + 2097152;         // [bh,n,d]
    uint16_t* vt   = k + 2097152;         // [bh,d,n]
    uint16_t* cc   = vt + 2097152;        // [b,n,c]
    float*    pet  = (float*)(cc + 2097152);  // [256][64]

    wconv_pe<<<1088, 256, 0, stream>>>(Wq, Wk, Wv, Wo, Wb, pet);
    qkv_gemm<<<dim3(128, 4), 256, 0, stream>>>(x, pet, Wb, bq, bk, bv, q, k, vt);
    flash<<<dim3(32, 16), 512, 0, stream>>>(q, k, vt, cc);
    proj_gemm<<<dim3(128, 4), 256, 0, stream>>>(cc, Wb + 3 * 65536, bo, out);
}

// Round 10
// 133.835 us; speedup vs baseline: 1.1145x; 1.1145x over previous
//
#include <hip/hip_runtime.h>
#include <hip/hip_bf16.h>
#include <cstdint>

typedef float f32x4 __attribute__((ext_vector_type(4)));
typedef __bf16 bf16x8 __attribute__((ext_vector_type(8)));
typedef uint32_t uint2v __attribute__((ext_vector_type(2)));

#define MFMA_K32(A, B, C) __builtin_amdgcn_mfma_f32_16x16x32_bf16((A), (B), (C), 0, 0, 0)

#if __has_builtin(__builtin_amdgcn_exp2f)
#define EXP2(x) __builtin_amdgcn_exp2f(x)
#else
#define EXP2(x) exp2f(x)
#endif

// round-to-nearest-even f32 -> bf16 bits
static __device__ __forceinline__ uint16_t f2b(float f) {
    uint32_t u = __float_as_uint(f);
    uint32_t r = (u + 0x7fffu + ((u >> 16) & 1u)) >> 16;
    return (uint16_t)r;
}

// pack two f32 -> bf16x2 dword (low = a, high = b), RNE.
// m240: no builtin on gfx950 -- MUST be inline asm, else a ~7-op SW fallback
// compiles and dominates the VALU budget (R8: flash 65->49.6 us from this).
static __device__ __forceinline__ uint32_t packbf(float a, float b) {
    uint32_t r;
    asm("v_cvt_pk_bf16_f32 %0, %1, %2" : "=v"(r) : "v"(a), "v"(b));
    return r;
}

// ---------------- kernel 0: prep = peadd-tile OR W-convert per block -----
// bid < 512 : tok = transpose(x + PE) for one 64n x 64c tile, PE inline
//             (verified body from the R6/R7 fused runs).
// bid >= 512: W f32->bf16, one element per thread (512 blocks x 512 thr).
// The two halves are data-independent -- merging removes one launch + gap.
__global__ __launch_bounds__(512) void prep(const float* __restrict__ x,
                                            const float* __restrict__ wq,
                                            const float* __restrict__ wk,
                                            const float* __restrict__ wv,
                                            const float* __restrict__ wo,
                                            uint16_t* __restrict__ dst,
                                            uint16_t* __restrict__ tok) {
    __shared__ uint16_t T[64][65];
    int tid = threadIdx.x, bid = blockIdx.x;
    if (bid < 512) {
        int nt = bid & 63, ct = (bid >> 6) & 3, bb = bid >> 8;
        int n0 = nt << 6, c0 = ct << 6;
        int nl = tid & 63, cq = tid >> 6;  // cq 0..7, 8 channels each
        int n = n0 + nl;
        // PE arg: width channels (c<128) use pos-in-row (nl); height use row (nt)
        float pf = (float)((c0 & 128) ? nt : nl);
        int cbase = c0 + cq * 8;
        int ibase = (cbase & 127) >> 1;
        // div_term recurrence: dt_i = exp(2i * -ln(1e4)/128), ratio exp(-2c)
        float dt = __expf((float)(2 * ibase) * -0.07195578415606394f);
#pragma unroll
        for (int j = 0; j < 4; ++j) {
            float sv, cv;
            __sincosf(pf * dt, &sv, &cv);
            int cl = cq * 8 + 2 * j;
            int cc = cbase + 2 * j;
            T[cl][nl]     = f2b(x[((size_t)(bb * 256 + cc) << 12) + n] + sv);
            T[cl + 1][nl] = f2b(x[((size_t)(bb * 256 + cc + 1) << 12) + n] + cv);
            dt *= 0.8659643233600653f;  // exp(-2*0.07195578415606394)
        }
        __syncthreads();
#pragma unroll
        for (int p = 0; p < 8; ++p) {
            int tl = cq * 8 + p;
            tok[(((size_t)(bb << 12) | (n0 + tl)) << 8) + c0 + nl] = T[nl][tl];
        }
    } else {
        int idx = (bid - 512) * 512 + tid;  // 0..262143
        int which = idx >> 16, off = idx & 65535;
        const float* s = (which == 0) ? wq : (which == 1) ? wk : (which == 2) ? wv : wo;
        dst[idx] = f2b(s[off]);
    }
}

// ---------------- kernel 1: QKV projection, W LDS-staged ------------------
// grid (128 mtiles, 4 otiles), 256 thr = 4 waves. D[o][n].
__global__ __launch_bounds__(256) void qkv_gemm(const uint16_t* __restrict__ tok,
                                                const uint16_t* __restrict__ Wall,
                                                const float* __restrict__ bq,
                                                const float* __restrict__ bk,
                                                const float* __restrict__ bv,
                                                uint16_t* __restrict__ qo,
                                                uint16_t* __restrict__ ko,
                                                uint16_t* __restrict__ vo) {
    __shared__ __align__(16) uint16_t WS[64][264];
    int tid = threadIdx.x, wv = tid >> 6, lane = tid & 63;
    int c16 = lane & 15, quad = lane >> 4;
    int M0 = blockIdx.x * 64 + wv * 16;
    int O0 = blockIdx.y * 64;
    const uint16_t* arow = tok + (size_t)(M0 + c16) * 256;
    bf16x8 af[8];
#pragma unroll
    for (int kk = 0; kk < 8; ++kk) af[kk] = *(const bf16x8*)(arow + kk * 32 + quad * 8);
    f32x4 zero = {0.f, 0.f, 0.f, 0.f};
    int bb = M0 >> 12, n = (M0 + c16) & 4095;
    int srow = tid >> 5, sch = (tid & 31) << 3;  // staging: 2048 elems/pass
    for (int mat = 0; mat < 3; ++mat) {
        const uint16_t* Wg = Wall + (size_t)mat * 65536 + (size_t)O0 * 256;
        __syncthreads();  // previous WS readers done
#pragma unroll
        for (int p = 0; p < 8; ++p)
            *(bf16x8*)(&WS[p * 8 + srow][sch]) = *(const bf16x8*)(Wg + (p * 8 + srow) * 256 + sch);
        __syncthreads();
        f32x4 acc[4] = {zero, zero, zero, zero};
#pragma unroll
        for (int kk = 0; kk < 8; ++kk) {
            int k0 = kk * 32 + quad * 8;
#pragma unroll
            for (int nb = 0; nb < 4; ++nb)
                acc[nb] = MFMA_K32(*(const bf16x8*)(&WS[nb * 16 + c16][k0]),
                                   af[kk], acc[nb]);  // D[o][n]
        }
        const float* bias = (mat == 0) ? bq : (mat == 1) ? bk : bv;
        if (mat < 2) {
            // q gets 1/sqrt(32)*log2(e) folded in (softmax uses exp2)
            float scale = (mat == 0) ? 0.25505654134660127f : 1.0f;
            uint16_t* dst = (mat == 0) ? qo : ko;
#pragma unroll
            for (int nb = 0; nb < 4; ++nb) {
                int o = O0 + nb * 16 + quad * 4;          // o..o+3, same head
                f32x4 bi = *(const f32x4*)(bias + o);
                int h = o >> 5, dd = o & 31;
                uint2v pk;
                pk[0] = packbf((acc[nb][0] + bi[0]) * scale, (acc[nb][1] + bi[1]) * scale);
                pk[1] = packbf((acc[nb][2] + bi[2]) * scale, (acc[nb][3] + bi[3]) * scale);
                *(uint2v*)(dst + ((size_t)(bb * 8 + h) * 4096 + n) * 32 + dd) = pk;
            }
        } else {
            // V^T [bh,d,n]
#pragma unroll
            for (int nb = 0; nb < 4; ++nb)
#pragma unroll
                for (int r = 0; r < 4; ++r) {
                    int o = O0 + nb * 16 + quad * 4 + r;
                    vo[((size_t)(bb * 8 + (o >> 5)) * 32 + (o & 31)) * 4096 + n] =
                        f2b(acc[nb][r] + bias[o]);
                }
        }
    }
}

// ---------------- kernel 2: flash attention, LDS-staged + in-block k-split
// grid (32 qtiles of 128, 16 bh), block 512 = 8 waves; wave owns 32 q rows.
// K32 path everywhere: QK A-operand rows are PERMUTED so each lane's two
// 4-element sub-chunk score registers cover physical k = quad*8..quad*8+7 ==
// the 16x16x32 A-fragment layout. Dual q-blocks interleaved. Row-sum l via
// ones-frag MFMA.
__global__ __launch_bounds__(512, 4) void flash(const uint16_t* __restrict__ qb,
                                                const uint16_t* __restrict__ kb,
                                                const uint16_t* __restrict__ vtb,
                                                uint16_t* __restrict__ concat) {
    // per half: KT[2][64][40] (10240 B) + VT[2][32][72] (9216 B) = 19456 B
    __shared__ __align__(16) char smem[38912];
    int tid = threadIdx.x, wv = tid >> 6, lane = tid & 63;
    int c16 = lane & 15, quad = lane >> 4;
    int half = tid >> 8, t2 = tid & 255;
    int bh = blockIdx.y;
    int q0 = (blockIdx.x << 7) + (wv & 3) * 32;
    size_t base = (size_t)bh << 12;

    uint16_t* KT = (uint16_t*)(smem + half * 19456);          // [2][64][40]
    uint16_t* VT = (uint16_t*)(smem + half * 19456 + 10240);  // [2][32][72]

    const uint16_t* kgp = kb + (base + (size_t)half * 2048 + (t2 >> 2)) * 32 + (t2 & 3) * 8;
    const uint16_t* vgp = vtb + ((size_t)bh * 32 + (t2 >> 3)) * 4096 + half * 2048 + (t2 & 7) * 8;
    uint16_t* kls = KT + (t2 >> 2) * 40 + (t2 & 3) * 8;   // + buf*2560
    uint16_t* vls = VT + (t2 >> 3) * 72 + (t2 & 7) * 8;   // + buf*2304

    bf16x8 qf0 = *(const bf16x8*)(qb + (base + q0 + c16) * 32 + quad * 8);
    bf16x8 qf1 = *(const bf16x8*)(qb + (base + q0 + 16 + c16) * 32 + quad * 8);

    // permuted K-row base for the QK A-operand
    int rbase = ((c16 >> 2) << 3) + (c16 & 3);

    union { uint32_t u[4]; bf16x8 v; } onesu;
    onesu.u[0] = 0x3F803F80u; onesu.u[1] = 0x3F803F80u;
    onesu.u[2] = 0x3F803F80u; onesu.u[3] = 0x3F803F80u;
    bf16x8 ones = onesu.v;

    f32x4 zero = {0.f, 0.f, 0.f, 0.f};
    f32x4 o00 = zero, o01 = zero, o10 = zero, o11 = zero;
    f32x4 oS0 = zero, oS1 = zero;

    // prologue: stage tile 0 into buf 0
    {
        bf16x8 kr = *(const bf16x8*)kgp;
        bf16x8 vr = *(const bf16x8*)vgp;
        *(bf16x8*)kls = kr;
        *(bf16x8*)vls = vr;
    }
    __syncthreads();

    for (int kt = 0; kt < 32; ++kt) {
        int cur = kt & 1;
        int kn = (kt + 1) & 31;  // last iter re-loads tile 0 (in-bounds, unused)
        bf16x8 kr = *(const bf16x8*)(kgp + (size_t)kn * 2048);
        bf16x8 vr = *(const bf16x8*)(vgp + kn * 64);
        const uint16_t* kfp = KT + cur * 2560 + rbase * 40 + quad * 8;
        const uint16_t* vfp = VT + cur * 2304 + c16 * 72 + quad * 8;
        bf16x8 kf[4], vA[2], vB[2];
        kf[0] = *(const bf16x8*)(kfp);                 // p0 j0: rows rbase
        kf[1] = *(const bf16x8*)(kfp + 160);           // p0 j1: rows rbase+4
        kf[2] = *(const bf16x8*)(kfp + 1280);          // p1 j0: rows rbase+32
        kf[3] = *(const bf16x8*)(kfp + 1440);          // p1 j1: rows rbase+36
        vA[0] = *(const bf16x8*)(vfp);                 // d=c16,    seq quad*8
        vA[1] = *(const bf16x8*)(vfp + 32);            // d=c16,    seq 32+quad*8
        vB[0] = *(const bf16x8*)(vfp + 1152);          // d=16+c16, seq quad*8
        vB[1] = *(const bf16x8*)(vfp + 1152 + 32);     // d=16+c16, seq 32+quad*8

        // QK^T for both q-blocks: 8 independent MFMAs
        f32x4 s0[4], s1[4];
#pragma unroll
        for (int c = 0; c < 4; ++c) s0[c] = MFMA_K32(kf[c], qf0, zero);
#pragma unroll
        for (int c = 0; c < 4; ++c) s1[c] = MFMA_K32(kf[c], qf1, zero);

        // exp2 -> pack -> PV, two independent chains per p
#pragma unroll
        for (int p = 0; p < 2; ++p) {
#pragma unroll
            for (int r = 0; r < 4; ++r) {
                s0[2 * p][r] = EXP2(s0[2 * p][r]);
                s0[2 * p + 1][r] = EXP2(s0[2 * p + 1][r]);
                s1[2 * p][r] = EXP2(s1[2 * p][r]);
                s1[2 * p + 1][r] = EXP2(s1[2 * p + 1][r]);
            }
            union { bf16x8 v; uint32_t u[4]; } pa0, pa1;
            pa0.u[0] = packbf(s0[2 * p][0], s0[2 * p][1]);
            pa0.u[1] = packbf(s0[2 * p][2], s0[2 * p][3]);
            pa0.u[2] = packbf(s0[2 * p + 1][0], s0[2 * p + 1][1]);
            pa0.u[3] = packbf(s0[2 * p + 1][2], s0[2 * p + 1][3]);
            pa1.u[0] = packbf(s1[2 * p][0], s1[2 * p][1]);
            pa1.u[1] = packbf(s1[2 * p][2], s1[2 * p][3]);
            pa1.u[2] = packbf(s1[2 * p + 1][0], s1[2 * p + 1][1]);
            pa1.u[3] = packbf(s1[2 * p + 1][2], s1[2 * p + 1][3]);
            o00 = MFMA_K32(pa0.v, vA[p], o00);
            o01 = MFMA_K32(pa0.v, vB[p], o01);
            oS0 = MFMA_K32(pa0.v, ones, oS0);
            o10 = MFMA_K32(pa1.v, vA[p], o10);
            o11 = MFMA_K32(pa1.v, vB[p], o11);
            oS1 = MFMA_K32(pa1.v, ones, oS1);
        }

        *(bf16x8*)(kls + (cur ^ 1) * 2560) = kr;
        *(bf16x8*)(vls + (cur ^ 1) * 2304) = vr;
        __syncthreads();
    }

    // combine the two k-halves via LDS (staging area is dead now)
    float* ov = (float*)smem;  // [4][64][25] = 25600 B
    if (wv >= 4) {
        float* d = ov + ((wv - 4) * 64 + lane) * 25;
#pragma unroll
        for (int r = 0; r < 4; ++r) {
            d[r] = o00[r]; d[4 + r] = o01[r]; d[8 + r] = o10[r]; d[12 + r] = o11[r];
            d[16 + r] = oS0[r]; d[20 + r] = oS1[r];
        }
    }
    __syncthreads();
    if (wv < 4) {
        const float* s = ov + (wv * 64 + lane) * 25;
#pragma unroll
        for (int r = 0; r < 4; ++r) {
            o00[r] += s[r]; o01[r] += s[4 + r]; o10[r] += s[8 + r]; o11[r] += s[12 + r];
            oS0[r] += s[16 + r]; oS1[r] += s[20 + r];
        }
        int h = bh & 7, bb = bh >> 3;
#pragma unroll
        for (int r = 0; r < 4; ++r) {
            float i0 = 1.f / oS0[r];   // l row-aligned with o rows: no shuffle
            float i1 = 1.f / oS1[r];
            int n = q0 + quad * 4 + r;
            size_t row0 = ((size_t)bb * 4096 + n) * 256 + h * 32;
            size_t row1 = ((size_t)bb * 4096 + n + 16) * 256 + h * 32;
            concat[row0 + c16]      = f2b(o00[r] * i0);
            concat[row0 + 16 + c16] = f2b(o01[r] * i0);
            concat[row1 + c16]      = f2b(o10[r] * i1);
            concat[row1 + 16 + c16] = f2b(o11[r] * i1);
        }
    }
}

// ---------------- kernel 3: output projection, W LDS-staged --------------
__global__ __launch_bounds__(256) void proj_gemm(const uint16_t* __restrict__ concat,
                                                 const uint16_t* __restrict__ Wo,
                                                 const float* __restrict__ bo,
                                                 float* __restrict__ out) {
    __shared__ __align__(16) uint16_t WS[64][264];
    int tid = threadIdx.x, wv = tid >> 6, lane = tid & 63;
    int c16 = lane & 15, quad = lane >> 4;
    int M0 = blockIdx.x * 64 + wv * 16;
    int O0 = blockIdx.y * 64;
    int srow = tid >> 5, sch = (tid & 31) << 3;
    const uint16_t* Wg = Wo + (size_t)O0 * 256;
#pragma unroll
    for (int p = 0; p < 8; ++p)
        *(bf16x8*)(&WS[p * 8 + srow][sch]) = *(const bf16x8*)(Wg + (p * 8 + srow) * 256 + sch);
    const uint16_t* crow = concat + (size_t)(M0 + c16) * 256;
    bf16x8 af[8];
#pragma unroll
    for (int kk = 0; kk < 8; ++kk) af[kk] = *(const bf16x8*)(crow + kk * 32 + quad * 8);
    __syncthreads();
    f32x4 zero = {0.f, 0.f, 0.f, 0.f};
    f32x4 acc[4] = {zero, zero, zero, zero};
#pragma unroll
    for (int kk = 0; kk < 8; ++kk) {
        int k0 = kk * 32 + quad * 8;
#pragma unroll
        for (int nb = 0; nb < 4; ++nb)
            acc[nb] = MFMA_K32(*(const bf16x8*)(&WS[nb * 16 + c16][k0]),
                               af[kk], acc[nb]);  // D[o][token]
    }
    int bb = M0 >> 12, n = (M0 + c16) & 4095;
#pragma unroll
    for (int nb = 0; nb < 4; ++nb)
#pragma unroll
        for (int r = 0; r < 4; ++r) {
            int o = O0 + nb * 16 + quad * 4 + r;
            out[((size_t)(bb * 256 + o) << 12) + n] = acc[nb][r] + bo[o];
        }
}

extern "C" void kernel_launch(void* const* d_in, const int* in_sizes, int n_in,
                              void* d_out, int out_size, void* d_ws, size_t ws_size,
                              hipStream_t stream) {
    const float* x  = (const float*)d_in[0];
    const float* Wq = (const float*)d_in[1];
    const float* bq = (const float*)d_in[2];
    const float* Wk = (const float*)d_in[3];
    const float* bk = (const float*)d_in[4];
    const float* Wv = (const float*)d_in[5];
    const float* bv = (const float*)d_in[6];
    const float* Wo = (const float*)d_in[7];
    const float* bo = (const float*)d_in[8];
    float* out = (float*)d_out;

    uint16_t* ws   = (uint16_t*)d_ws;
    uint16_t* Wb   = ws;                  // 4*65536 bf16
    uint16_t* tok  = Wb + 4 * 65536;      // [b,N,c]
    uint16_t* q    = tok + 2097152;       // [bh,n,d]
    uint16_t* k    = q + 2097152;         // [bh,n,d]
    uint16_t* vt   = k + 2097152;         // [bh,d,n]
    uint16_t* cc   = vt + 2097152;        // [b,n,c]

    prep<<<1024, 512, 0, stream>>>(x, Wq, Wk, Wv, Wo, Wb, tok);
    qkv_gemm<<<dim3(128, 4), 256, 0, stream>>>(tok, Wb, bq, bk, bv, q, k, vt);
    flash<<<dim3(32, 16), 512, 0, stream>>>(q, k, vt, cc);
    proj_gemm<<<dim3(128, 4), 256, 0, stream>>>(cc, Wb + 3 * 65536, bo, out);
}